// Round 3
// baseline (288.714 us; speedup 1.0000x reference)
//
#include <hip/hip_runtime.h>

#define B_SZ 1024
#define H_SZ 2048
#define E_SZ 1024

typedef float  f32x4 __attribute__((ext_vector_type(4)));
typedef short  s16x8 __attribute__((ext_vector_type(8)));

__device__ __forceinline__ unsigned short f2bf(float f) {
    unsigned u = __float_as_uint(f);
    u = u + 0x7fffu + ((u >> 16) & 1u);   // RNE
    return (unsigned short)(u >> 16);
}
__device__ __forceinline__ float bf2f(unsigned short s) {
    return __uint_as_float(((unsigned)s) << 16);
}
__device__ __forceinline__ float sigm(float v) {
    return 1.0f / (1.0f + __expf(-v));
}

// ---------------------------------------------------------------- cast pass
struct CastArgs {
    const float*    src[11];
    unsigned short* dst[11];
    int             n[11];
};

__global__ __launch_bounds__(256) void cast_kernel(CastArgs a) {
    const int arr = blockIdx.y;
    const int n = a.n[arr];
    const float* __restrict__ s = a.src[arr];
    unsigned short* __restrict__ d = a.dst[arr];
    const int stride = gridDim.x * 256 * 4;
    for (int i = (blockIdx.x * 256 + threadIdx.x) * 4; i < n; i += stride) {
        float4 v = *(const float4*)(s + i);
        ushort4 o;
        o.x = f2bf(v.x); o.y = f2bf(v.y); o.z = f2bf(v.z); o.w = f2bf(v.w);
        *(ushort4*)(d + i) = o;
    }
}

// ------------------------------------------------- m97-style bf16 GEMM core
// acc += A[128 rows @ m0][kLen] @ W[128 rows @ n0][kLen]^T
// A,W row stride = ld elements (pre-offset base pointers for split-K).
__device__ __forceinline__ void gemm_accum(
    const unsigned short* __restrict__ A,
    const unsigned short* __restrict__ W,
    int ld, int kLen, int m0, int n0,
    unsigned short* lA, unsigned short* lB,
    f32x4 acc[4][4], int t)
{
    const int lane = t & 63;
    const int w    = t >> 6;
    const int wr   = (w >> 1) << 6;   // wave row offset in 128-tile
    const int wc   = (w & 1) << 6;    // wave col offset
    const int lr   = lane & 15;
    const int kq   = (lane >> 4) << 3;

    const int r0   = t >> 2;          // staging row for chunk t (0..63)
    const int col0 = (t & 3) << 3;    // staging col (elements)

    for (int k0 = 0; k0 < kLen; k0 += 32) {
        const unsigned short* ga0 = A + (size_t)(m0 + r0) * ld + (k0 + col0);
        const unsigned short* ga1 = ga0 + (size_t)64 * ld;
        const unsigned short* gb0 = W + (size_t)(n0 + r0) * ld + (k0 + col0);
        const unsigned short* gb1 = gb0 + (size_t)64 * ld;
        __builtin_amdgcn_global_load_lds(
            (const __attribute__((address_space(1))) unsigned int*)ga0,
            (__attribute__((address_space(3))) unsigned int*)(lA + t * 8), 16, 0, 0);
        __builtin_amdgcn_global_load_lds(
            (const __attribute__((address_space(1))) unsigned int*)ga1,
            (__attribute__((address_space(3))) unsigned int*)(lA + (t + 256) * 8), 16, 0, 0);
        __builtin_amdgcn_global_load_lds(
            (const __attribute__((address_space(1))) unsigned int*)gb0,
            (__attribute__((address_space(3))) unsigned int*)(lB + t * 8), 16, 0, 0);
        __builtin_amdgcn_global_load_lds(
            (const __attribute__((address_space(1))) unsigned int*)gb1,
            (__attribute__((address_space(3))) unsigned int*)(lB + (t + 256) * 8), 16, 0, 0);
        __syncthreads();

        s16x8 af[4], bfr[4];
#pragma unroll
        for (int i = 0; i < 4; ++i)
            af[i] = *(const s16x8*)(lA + (wr + i * 16 + lr) * 32 + kq);
#pragma unroll
        for (int j = 0; j < 4; ++j)
            bfr[j] = *(const s16x8*)(lB + (wc + j * 16 + lr) * 32 + kq);
#pragma unroll
        for (int i = 0; i < 4; ++i)
#pragma unroll
            for (int j = 0; j < 4; ++j)
                acc[i][j] = __builtin_amdgcn_mfma_f32_16x16x32_bf16(
                    af[i], bfr[j], acc[i][j], 0, 0, 0);
        __syncthreads();
    }
}

// ------------------------------------------- gate GEMMs, split-K by 2
// 1024 blocks (4/CU). Work item = (nt 0..63, m 0..7, s 0..1).
// s=0: all of E (32 steps) + H[0:512) (16 steps); s=1: H[512:2048) (48 steps).
// Partials bf16 into part[(s*4+q)*BH + m*H + n]; bias/activation deferred
// to combine_kernel. XCD swizzle: each XCD owns 8 contiguous nt.
__global__ __launch_bounds__(256) void gates_kernel(
    const unsigned short* __restrict__ Xb,
    const unsigned short* __restrict__ Hb,
    const unsigned short* __restrict__ Wxb,
    const unsigned short* __restrict__ Whb,
    unsigned short* __restrict__ part)
{
    __shared__ unsigned short lA[128 * 32];
    __shared__ unsigned short lB[128 * 32];
    const int t   = threadIdx.x;
    const int b   = blockIdx.x;
    const int xcd = b & 7;
    const int i_  = b >> 3;                 // 0..127 within XCD
    const int nt  = xcd * 8 + (i_ >> 4);    // 0..63 weight tile (q,n0)
    const int rem = i_ & 15;
    const int m0  = (rem & 7) * 128;
    const int s   = rem >> 3;
    const int q   = nt >> 4;
    const int n0  = (nt & 15) * 128;

    f32x4 acc[4][4] = {};
    if (s == 0) {
        gemm_accum(Xb, Wxb + (size_t)q * H_SZ * E_SZ, E_SZ, E_SZ, m0, n0, lA, lB, acc, t);
        gemm_accum(Hb, Whb + (size_t)q * H_SZ * H_SZ, H_SZ, 512, m0, n0, lA, lB, acc, t);
    } else {
        gemm_accum(Hb + 512, Whb + (size_t)q * H_SZ * H_SZ + 512, H_SZ, 1536,
                   m0, n0, lA, lB, acc, t);
    }

    const int lane = t & 63, w = t >> 6;
    const int wr = (w >> 1) << 6, wc = (w & 1) << 6;
    const int lr = lane & 15, rq = (lane >> 4) << 2;
    unsigned short* P = part + (size_t)(s * 4 + q) * B_SZ * H_SZ;
#pragma unroll
    for (int i = 0; i < 4; ++i) {
#pragma unroll
        for (int j = 0; j < 4; ++j) {
            const int n = n0 + wc + j * 16 + lr;
#pragma unroll
            for (int r = 0; r < 4; ++r) {
                const int m = m0 + wr + i * 16 + rq + r;
                P[(size_t)m * H_SZ + n] = f2bf(acc[i][j][r]);
            }
        }
    }
}

// -------------------------------- combine: bias + activations + cell update
__global__ __launch_bounds__(256) void combine_kernel(
    const unsigned short* __restrict__ part,
    const float* __restrict__ bi, const float* __restrict__ bg,
    const float* __restrict__ bff, const float* __restrict__ bo,
    const float* __restrict__ c,
    float* __restrict__ c_out, float* __restrict__ h_out,
    unsigned short* __restrict__ HnB)
{
    const size_t BH = (size_t)B_SZ * H_SZ;
    const int idx = (blockIdx.x * 256 + threadIdx.x) * 4;
    const int col = idx & (H_SZ - 1);

    float v[4][4];   // [q][elem]
#pragma unroll
    for (int q = 0; q < 4; ++q) {
        ushort4 p0 = *(const ushort4*)(part + (size_t)q * BH + idx);
        ushort4 p1 = *(const ushort4*)(part + (size_t)(4 + q) * BH + idx);
        v[q][0] = bf2f(p0.x) + bf2f(p1.x);
        v[q][1] = bf2f(p0.y) + bf2f(p1.y);
        v[q][2] = bf2f(p0.z) + bf2f(p1.z);
        v[q][3] = bf2f(p0.w) + bf2f(p1.w);
    }
    float4 bvi = *(const float4*)(bi + col);
    float4 bvg = *(const float4*)(bg + col);
    float4 bvf = *(const float4*)(bff + col);
    float4 bvo = *(const float4*)(bo + col);
    float4 cv  = *(const float4*)(c + idx);

    const float bi_[4] = {bvi.x, bvi.y, bvi.z, bvi.w};
    const float bg_[4] = {bvg.x, bvg.y, bvg.z, bvg.w};
    const float bf_[4] = {bvf.x, bvf.y, bvf.z, bvf.w};
    const float bo_[4] = {bvo.x, bvo.y, bvo.z, bvo.w};
    const float c_[4]  = {cv.x, cv.y, cv.z, cv.w};

    float cn[4], hn[4];
#pragma unroll
    for (int e = 0; e < 4; ++e) {
        const float iv = sigm(v[0][e] + bi_[e]);
        const float gv = tanhf(v[1][e] + bg_[e]);
        const float fv = sigm(v[2][e] + bf_[e]);
        const float ov = sigm(v[3][e] + bo_[e]);
        cn[e] = fv * c_[e] + iv * gv;
        hn[e] = ov * cn[e];
    }
    *(float4*)(c_out + idx) = make_float4(cn[0], cn[1], cn[2], cn[3]);
    *(float4*)(h_out + idx) = make_float4(hn[0], hn[1], hn[2], hn[3]);
    ushort4 hb;
    hb.x = f2bf(hn[0]); hb.y = f2bf(hn[1]); hb.z = f2bf(hn[2]); hb.w = f2bf(hn[3]);
    *(ushort4*)(HnB + idx) = hb;
}

// ---------------------------------------------------- y GEMM, split-K by 4
// 256 blocks (1/CU): (m 0..7) x (n 0..7) x (s 0..3), K-chunk = 512.
__global__ __launch_bounds__(256) void y_split_kernel(
    const unsigned short* __restrict__ Hn,
    const unsigned short* __restrict__ Wy,
    float* __restrict__ part)
{
    __shared__ unsigned short lA[128 * 32];
    __shared__ unsigned short lB[128 * 32];
    const int t   = threadIdx.x;
    const int b   = blockIdx.x;
    const int xcd = b & 7;
    const int i_  = b >> 3;                 // 0..31 within XCD
    const int ns  = xcd * 4 + (i_ >> 3);    // 0..31: (n-tile, split)
    const int m0  = (i_ & 7) * 128;
    const int n0  = (ns >> 2) * 128;
    const int s   = ns & 3;

    f32x4 acc[4][4] = {};
    gemm_accum(Hn + s * 512, Wy + s * 512, H_SZ, 512, m0, n0, lA, lB, acc, t);

    const int lane = t & 63, w = t >> 6;
    const int wr = (w >> 1) << 6, wc = (w & 1) << 6;
    const int lr = lane & 15, rq = (lane >> 4) << 2;
    float* P = part + (size_t)s * B_SZ * E_SZ;
#pragma unroll
    for (int i = 0; i < 4; ++i) {
#pragma unroll
        for (int j = 0; j < 4; ++j) {
            const int n = n0 + wc + j * 16 + lr;
#pragma unroll
            for (int r = 0; r < 4; ++r) {
                const int m = m0 + wr + i * 16 + rq + r;
                P[(size_t)m * E_SZ + n] = acc[i][j][r];
            }
        }
    }
}

__global__ __launch_bounds__(256) void y_reduce_kernel(
    const float* __restrict__ part, const float* __restrict__ by,
    float* __restrict__ yout)
{
    const size_t BE = (size_t)B_SZ * E_SZ;
    const int idx = (blockIdx.x * 256 + threadIdx.x) * 4;
    float4 a = *(const float4*)(part + idx);
    float4 b2 = *(const float4*)(part + BE + idx);
    float4 c2 = *(const float4*)(part + 2 * BE + idx);
    float4 d2 = *(const float4*)(part + 3 * BE + idx);
    const int col = idx & (E_SZ - 1);
    float4 bv = *(const float4*)(by + col);
    float4 o;
    o.x = tanhf(a.x + b2.x + c2.x + d2.x + bv.x);
    o.y = tanhf(a.y + b2.y + c2.y + d2.y + bv.y);
    o.z = tanhf(a.z + b2.z + c2.z + d2.z + bv.z);
    o.w = tanhf(a.w + b2.w + c2.w + d2.w + bv.w);
    *(float4*)(yout + idx) = o;
}

// ---------------------------------------------------------------- launch
extern "C" void kernel_launch(void* const* d_in, const int* in_sizes, int n_in,
                              void* d_out, int out_size, void* d_ws, size_t ws_size,
                              hipStream_t stream) {
    const float* x   = (const float*)d_in[0];
    const float* c   = (const float*)d_in[1];
    const float* h   = (const float*)d_in[2];
    const float* Wxi = (const float*)d_in[3];
    const float* Whi = (const float*)d_in[4];
    const float* Bi  = (const float*)d_in[5];
    const float* Wxg = (const float*)d_in[6];
    const float* Whg = (const float*)d_in[7];
    const float* Bg  = (const float*)d_in[8];
    const float* Wxf = (const float*)d_in[9];
    const float* Whf = (const float*)d_in[10];
    const float* Bf  = (const float*)d_in[11];
    const float* Wxo = (const float*)d_in[12];
    const float* Who = (const float*)d_in[13];
    const float* Bo  = (const float*)d_in[14];
    const float* Why = (const float*)d_in[15];
    const float* By  = (const float*)d_in[16];

    const size_t BE = (size_t)B_SZ * E_SZ, BH = (size_t)B_SZ * H_SZ;
    const size_t HE = (size_t)H_SZ * E_SZ, HH = (size_t)H_SZ * H_SZ;
    const size_t EH = (size_t)E_SZ * H_SZ;

    unsigned short* ws   = (unsigned short*)d_ws;
    unsigned short* Xb   = ws;                 // BE
    unsigned short* Hb   = Xb + BE;            // BH
    unsigned short* Wxb  = Hb + BH;            // 4*HE
    unsigned short* Whb  = Wxb + 4 * HE;       // 4*HH
    unsigned short* Whyb = Whb + 4 * HH;       // EH
    unsigned short* Gp   = Whyb + EH;          // 8*BH bf16 gate partials (32 MB);
                                               // later reused as fp32 y-partials (16 MB)
    unsigned short* HnB  = Gp + 8 * BH;        // BH

    CastArgs ca;
    ca.src[0]  = x;   ca.dst[0]  = Xb;           ca.n[0]  = (int)BE;
    ca.src[1]  = h;   ca.dst[1]  = Hb;           ca.n[1]  = (int)BH;
    ca.src[2]  = Wxi; ca.dst[2]  = Wxb;          ca.n[2]  = (int)HE;
    ca.src[3]  = Wxg; ca.dst[3]  = Wxb + HE;     ca.n[3]  = (int)HE;
    ca.src[4]  = Wxf; ca.dst[4]  = Wxb + 2 * HE; ca.n[4]  = (int)HE;
    ca.src[5]  = Wxo; ca.dst[5]  = Wxb + 3 * HE; ca.n[5]  = (int)HE;
    ca.src[6]  = Whi; ca.dst[6]  = Whb;          ca.n[6]  = (int)HH;
    ca.src[7]  = Whg; ca.dst[7]  = Whb + HH;     ca.n[7]  = (int)HH;
    ca.src[8]  = Whf; ca.dst[8]  = Whb + 2 * HH; ca.n[8]  = (int)HH;
    ca.src[9]  = Who; ca.dst[9]  = Whb + 3 * HH; ca.n[9]  = (int)HH;
    ca.src[10] = Why; ca.dst[10] = Whyb;         ca.n[10] = (int)EH;

    hipLaunchKernelGGL(cast_kernel, dim3(1024, 11), dim3(256), 0, stream, ca);
    hipLaunchKernelGGL(gates_kernel, dim3(1024), dim3(256), 0, stream,
                       Xb, Hb, Wxb, Whb, Gp);

    float* y_out = (float*)d_out;
    float* c_out = y_out + BE;
    float* h_out = c_out + BH;
    hipLaunchKernelGGL(combine_kernel, dim3((unsigned)(BH / 1024)), dim3(256), 0, stream,
                       Gp, Bi, Bg, Bf, Bo, c, c_out, h_out, HnB);

    float* ypart = (float*)Gp;   // gate partials dead after combine
    hipLaunchKernelGGL(y_split_kernel, dim3(256), dim3(256), 0, stream,
                       HnB, Whyb, ypart);
    hipLaunchKernelGGL(y_reduce_kernel, dim3((unsigned)(BE / 1024)), dim3(256), 0, stream,
                       ypart, By, y_out);
}

// Round 4
// 287.100 us; speedup vs baseline: 1.0056x; 1.0056x over previous
//
#include <hip/hip_runtime.h>

#define B_SZ 1024
#define H_SZ 2048
#define E_SZ 1024

typedef float  f32x4 __attribute__((ext_vector_type(4)));
typedef short  s16x8 __attribute__((ext_vector_type(8)));

__device__ __forceinline__ unsigned short f2bf(float f) {
    unsigned u = __float_as_uint(f);
    u = u + 0x7fffu + ((u >> 16) & 1u);   // RNE
    return (unsigned short)(u >> 16);
}
__device__ __forceinline__ float bf2f(unsigned short s) {
    return __uint_as_float(((unsigned)s) << 16);
}
__device__ __forceinline__ float sigm(float v) {
    return 1.0f / (1.0f + __expf(-v));
}

__device__ __forceinline__ void gll(const unsigned short* g, unsigned short* l) {
    __builtin_amdgcn_global_load_lds(
        (const __attribute__((address_space(1))) unsigned int*)g,
        (__attribute__((address_space(3))) unsigned int*)l, 16, 0, 0);
}

// waitcnt immediates (gfx9 encoding: vm[3:0]+[15:14], exp[6:4], lgkm[11:8])
#define WC_VM4   0x0F74   // vmcnt(4), no exp/lgkm wait
#define WC_VM0   0x0F70   // vmcnt(0)
#define WC_LGKM0 0xC07F   // lgkmcnt(0), no vm/exp wait

// ---------------------------------------------------------------- cast pass
struct CastArgs {
    const float*    src[11];
    unsigned short* dst[11];
    int             n[11];
};

__global__ __launch_bounds__(256) void cast_kernel(CastArgs a) {
    const int arr = blockIdx.y;
    const int n = a.n[arr];
    const float* __restrict__ s = a.src[arr];
    unsigned short* __restrict__ d = a.dst[arr];
    const int stride = gridDim.x * 256 * 4;
    for (int i = (blockIdx.x * 256 + threadIdx.x) * 4; i < n; i += stride) {
        float4 v = *(const float4*)(s + i);
        ushort4 o;
        o.x = f2bf(v.x); o.y = f2bf(v.y); o.z = f2bf(v.z); o.w = f2bf(v.w);
        *(ushort4*)(d + i) = o;
    }
}

// ------------------------------------------- gate GEMMs, software-pipelined
// 512 blocks, full K (E-phase 32 steps + H-phase 64 steps = 96).
// Lookahead-2 double-buffered LDS, raw barriers + fine vmcnt so the wave
// never drains the loads it just issued. XCD swizzle as R2 (worked: 49 MB).
__global__ __launch_bounds__(256) void gates_kernel(
    const unsigned short* __restrict__ Xb,
    const unsigned short* __restrict__ Hb,
    const unsigned short* __restrict__ Wxb,
    const unsigned short* __restrict__ Whb,
    const float* __restrict__ bi, const float* __restrict__ bg,
    const float* __restrict__ bff, const float* __restrict__ bo,
    unsigned short* __restrict__ Z)
{
    __shared__ unsigned short lA[2 * 4096];
    __shared__ unsigned short lB[2 * 4096];
    const int t   = threadIdx.x;
    const int b   = blockIdx.x;
    const int xcd = b & 7;
    const int i_  = b >> 3;                 // 0..63 within XCD
    const int nt  = xcd * 8 + (i_ >> 3);    // 0..63 weight tile (q,n0)
    const int m0  = (i_ & 7) * 128;
    const int q   = nt >> 4;
    const int n0  = (nt & 15) * 128;

    const int r0   = t >> 2;
    const int col0 = (t & 3) << 3;

    const unsigned short* Wx = Wxb + (size_t)q * H_SZ * E_SZ;
    const unsigned short* Wh = Whb + (size_t)q * H_SZ * H_SZ;
    const unsigned short* baseAx = Xb + (size_t)(m0 + r0) * E_SZ + col0;
    const unsigned short* baseBx = Wx + (size_t)(n0 + r0) * E_SZ + col0;
    const unsigned short* baseAh = Hb + (size_t)(m0 + r0) * H_SZ + col0;
    const unsigned short* baseBh = Wh + (size_t)(n0 + r0) * H_SZ + col0;

    const int lane = t & 63, w = t >> 6;
    const int wr = (w >> 1) << 6, wc = (w & 1) << 6;
    const int lr = lane & 15, kq = (lane >> 4) << 3;

#define ISSUE(s, buf) do {                                                  \
        const unsigned short *a0_, *b0_; size_t st_;                        \
        if ((s) < 32) { a0_ = baseAx + (s) * 32; b0_ = baseBx + (s) * 32;   \
                        st_ = (size_t)64 * E_SZ; }                          \
        else          { a0_ = baseAh + ((s) - 32) * 32;                     \
                        b0_ = baseBh + ((s) - 32) * 32;                     \
                        st_ = (size_t)64 * H_SZ; }                          \
        unsigned short* la_ = lA + (buf) * 4096;                            \
        unsigned short* lb_ = lB + (buf) * 4096;                            \
        gll(a0_,       la_ + t * 8);                                        \
        gll(a0_ + st_, la_ + (t + 256) * 8);                                \
        gll(b0_,       lb_ + t * 8);                                        \
        gll(b0_ + st_, lb_ + (t + 256) * 8);                                \
    } while (0)

    f32x4 acc[4][4] = {};
    ISSUE(0, 0);
    ISSUE(1, 1);

    for (int k = 0; k < 96; ++k) {
        const int cur = k & 1;
        if (k < 95) __builtin_amdgcn_s_waitcnt(WC_VM4);
        else        __builtin_amdgcn_s_waitcnt(WC_VM0);
        __builtin_amdgcn_s_barrier();

        const unsigned short* la = lA + cur * 4096;
        const unsigned short* lb = lB + cur * 4096;
        s16x8 af[4], bfr[4];
#pragma unroll
        for (int i = 0; i < 4; ++i)
            af[i] = *(const s16x8*)(la + (wr + i * 16 + lr) * 32 + kq);
#pragma unroll
        for (int j = 0; j < 4; ++j)
            bfr[j] = *(const s16x8*)(lb + (wc + j * 16 + lr) * 32 + kq);

        __builtin_amdgcn_s_waitcnt(WC_LGKM0);   // frags in regs
        __builtin_amdgcn_s_barrier();           // all waves done reading cur
        if (k + 2 < 96) ISSUE(k + 2, cur);      // refill cur while we MFMA

#pragma unroll
        for (int i = 0; i < 4; ++i)
#pragma unroll
            for (int j = 0; j < 4; ++j)
                acc[i][j] = __builtin_amdgcn_mfma_f32_16x16x32_bf16(
                    af[i], bfr[j], acc[i][j], 0, 0, 0);
    }
#undef ISSUE

    const float* bias = (q == 0) ? bi : (q == 1) ? bg : (q == 2) ? bff : bo;
    const int rq = (lane >> 4) << 2;
    unsigned short* Zq = Z + (size_t)q * B_SZ * H_SZ;
#pragma unroll
    for (int i = 0; i < 4; ++i) {
#pragma unroll
        for (int j = 0; j < 4; ++j) {
            const int n = n0 + wc + j * 16 + lr;
            const float bv = bias[n];
#pragma unroll
            for (int r = 0; r < 4; ++r) {
                const int m = m0 + wr + i * 16 + rq + r;
                const float v = acc[i][j][r] + bv;
                const float a = (q == 1) ? tanhf(v) : sigm(v);
                Zq[(size_t)m * H_SZ + n] = f2bf(a);
            }
        }
    }
}

// ------------------------------------------------------------ cell update
__global__ __launch_bounds__(256) void cell_kernel(
    const unsigned short* __restrict__ Z, const float* __restrict__ c,
    float* __restrict__ c_out, float* __restrict__ h_out,
    unsigned short* __restrict__ HnB)
{
    const size_t BH = (size_t)B_SZ * H_SZ;
    const int idx = (blockIdx.x * 256 + threadIdx.x) * 4;
    ushort4 iu = *(const ushort4*)(Z + idx);
    ushort4 gu = *(const ushort4*)(Z + BH + idx);
    ushort4 fu = *(const ushort4*)(Z + 2 * BH + idx);
    ushort4 ou = *(const ushort4*)(Z + 3 * BH + idx);
    float4 cv = *(const float4*)(c + idx);

    float cn[4], hn[4];
    cn[0] = bf2f(fu.x) * cv.x + bf2f(iu.x) * bf2f(gu.x);
    cn[1] = bf2f(fu.y) * cv.y + bf2f(iu.y) * bf2f(gu.y);
    cn[2] = bf2f(fu.z) * cv.z + bf2f(iu.z) * bf2f(gu.z);
    cn[3] = bf2f(fu.w) * cv.w + bf2f(iu.w) * bf2f(gu.w);
    hn[0] = bf2f(ou.x) * cn[0];
    hn[1] = bf2f(ou.y) * cn[1];
    hn[2] = bf2f(ou.z) * cn[2];
    hn[3] = bf2f(ou.w) * cn[3];

    *(float4*)(c_out + idx) = make_float4(cn[0], cn[1], cn[2], cn[3]);
    *(float4*)(h_out + idx) = make_float4(hn[0], hn[1], hn[2], hn[3]);
    ushort4 hb;
    hb.x = f2bf(hn[0]); hb.y = f2bf(hn[1]); hb.z = f2bf(hn[2]); hb.w = f2bf(hn[3]);
    *(ushort4*)(HnB + idx) = hb;
}

// ------------------------------------- y GEMM, split-K by 4, pipelined
// 256 blocks: (m 0..7) x (n 0..7) x (s 0..3), K-chunk = 512 (16 steps).
__global__ __launch_bounds__(256) void y_split_kernel(
    const unsigned short* __restrict__ Hn,
    const unsigned short* __restrict__ Wy,
    float* __restrict__ part)
{
    __shared__ unsigned short lA[2 * 4096];
    __shared__ unsigned short lB[2 * 4096];
    const int t   = threadIdx.x;
    const int b   = blockIdx.x;
    const int xcd = b & 7;
    const int i_  = b >> 3;                 // 0..31 within XCD
    const int ns  = xcd * 4 + (i_ >> 3);    // 0..31: (n-tile, split)
    const int m0  = (i_ & 7) * 128;
    const int n0  = (ns >> 2) * 128;
    const int s   = ns & 3;

    const int r0   = t >> 2;
    const int col0 = (t & 3) << 3;
    const unsigned short* baseA = Hn + (size_t)(m0 + r0) * H_SZ + s * 512 + col0;
    const unsigned short* baseB = Wy + (size_t)(n0 + r0) * H_SZ + s * 512 + col0;
    const size_t st = (size_t)64 * H_SZ;

    const int lane = t & 63, w = t >> 6;
    const int wr = (w >> 1) << 6, wc = (w & 1) << 6;
    const int lr = lane & 15, kq = (lane >> 4) << 3;

#define ISSUE(sp, buf) do {                                                 \
        const unsigned short* a0_ = baseA + (sp) * 32;                      \
        const unsigned short* b0_ = baseB + (sp) * 32;                      \
        unsigned short* la_ = lA + (buf) * 4096;                            \
        unsigned short* lb_ = lB + (buf) * 4096;                            \
        gll(a0_,      la_ + t * 8);                                         \
        gll(a0_ + st, la_ + (t + 256) * 8);                                 \
        gll(b0_,      lb_ + t * 8);                                         \
        gll(b0_ + st, lb_ + (t + 256) * 8);                                 \
    } while (0)

    f32x4 acc[4][4] = {};
    ISSUE(0, 0);
    ISSUE(1, 1);
    for (int k = 0; k < 16; ++k) {
        const int cur = k & 1;
        if (k < 15) __builtin_amdgcn_s_waitcnt(WC_VM4);
        else        __builtin_amdgcn_s_waitcnt(WC_VM0);
        __builtin_amdgcn_s_barrier();
        const unsigned short* la = lA + cur * 4096;
        const unsigned short* lb = lB + cur * 4096;
        s16x8 af[4], bfr[4];
#pragma unroll
        for (int i = 0; i < 4; ++i)
            af[i] = *(const s16x8*)(la + (wr + i * 16 + lr) * 32 + kq);
#pragma unroll
        for (int j = 0; j < 4; ++j)
            bfr[j] = *(const s16x8*)(lb + (wc + j * 16 + lr) * 32 + kq);
        __builtin_amdgcn_s_waitcnt(WC_LGKM0);
        __builtin_amdgcn_s_barrier();
        if (k + 2 < 16) ISSUE(k + 2, cur);
#pragma unroll
        for (int i = 0; i < 4; ++i)
#pragma unroll
            for (int j = 0; j < 4; ++j)
                acc[i][j] = __builtin_amdgcn_mfma_f32_16x16x32_bf16(
                    af[i], bfr[j], acc[i][j], 0, 0, 0);
    }
#undef ISSUE

    const int rq = (lane >> 4) << 2;
    float* P = part + (size_t)s * B_SZ * E_SZ;
#pragma unroll
    for (int i = 0; i < 4; ++i) {
#pragma unroll
        for (int j = 0; j < 4; ++j) {
            const int n = n0 + wc + j * 16 + lr;
#pragma unroll
            for (int r = 0; r < 4; ++r) {
                const int m = m0 + wr + i * 16 + rq + r;
                P[(size_t)m * E_SZ + n] = acc[i][j][r];
            }
        }
    }
}

__global__ __launch_bounds__(256) void y_reduce_kernel(
    const float* __restrict__ part, const float* __restrict__ by,
    float* __restrict__ yout)
{
    const size_t BE = (size_t)B_SZ * E_SZ;
    const int idx = (blockIdx.x * 256 + threadIdx.x) * 4;
    float4 a = *(const float4*)(part + idx);
    float4 b2 = *(const float4*)(part + BE + idx);
    float4 c2 = *(const float4*)(part + 2 * BE + idx);
    float4 d2 = *(const float4*)(part + 3 * BE + idx);
    const int col = idx & (E_SZ - 1);
    float4 bv = *(const float4*)(by + col);
    float4 o;
    o.x = tanhf(a.x + b2.x + c2.x + d2.x + bv.x);
    o.y = tanhf(a.y + b2.y + c2.y + d2.y + bv.y);
    o.z = tanhf(a.z + b2.z + c2.z + d2.z + bv.z);
    o.w = tanhf(a.w + b2.w + c2.w + d2.w + bv.w);
    *(float4*)(yout + idx) = o;
}

// ---------------------------------------------------------------- launch
extern "C" void kernel_launch(void* const* d_in, const int* in_sizes, int n_in,
                              void* d_out, int out_size, void* d_ws, size_t ws_size,
                              hipStream_t stream) {
    const float* x   = (const float*)d_in[0];
    const float* c   = (const float*)d_in[1];
    const float* h   = (const float*)d_in[2];
    const float* Wxi = (const float*)d_in[3];
    const float* Whi = (const float*)d_in[4];
    const float* Bi  = (const float*)d_in[5];
    const float* Wxg = (const float*)d_in[6];
    const float* Whg = (const float*)d_in[7];
    const float* Bg  = (const float*)d_in[8];
    const float* Wxf = (const float*)d_in[9];
    const float* Whf = (const float*)d_in[10];
    const float* Bf  = (const float*)d_in[11];
    const float* Wxo = (const float*)d_in[12];
    const float* Who = (const float*)d_in[13];
    const float* Bo  = (const float*)d_in[14];
    const float* Why = (const float*)d_in[15];
    const float* By  = (const float*)d_in[16];

    const size_t BE = (size_t)B_SZ * E_SZ, BH = (size_t)B_SZ * H_SZ;
    const size_t HE = (size_t)H_SZ * E_SZ, HH = (size_t)H_SZ * H_SZ;
    const size_t EH = (size_t)E_SZ * H_SZ;

    unsigned short* ws   = (unsigned short*)d_ws;
    unsigned short* Xb   = ws;                 // BE
    unsigned short* Hb   = Xb + BE;            // BH
    unsigned short* Wxb  = Hb + BH;            // 4*HE
    unsigned short* Whb  = Wxb + 4 * HE;       // 4*HH
    unsigned short* Whyb = Whb + 4 * HH;       // EH
    unsigned short* Z    = Whyb + EH;          // 4*BH bf16; later fp32 y-partials
    unsigned short* HnB  = Z + 4 * BH;         // BH

    CastArgs ca;
    ca.src[0]  = x;   ca.dst[0]  = Xb;           ca.n[0]  = (int)BE;
    ca.src[1]  = h;   ca.dst[1]  = Hb;           ca.n[1]  = (int)BH;
    ca.src[2]  = Wxi; ca.dst[2]  = Wxb;          ca.n[2]  = (int)HE;
    ca.src[3]  = Wxg; ca.dst[3]  = Wxb + HE;     ca.n[3]  = (int)HE;
    ca.src[4]  = Wxf; ca.dst[4]  = Wxb + 2 * HE; ca.n[4]  = (int)HE;
    ca.src[5]  = Wxo; ca.dst[5]  = Wxb + 3 * HE; ca.n[5]  = (int)HE;
    ca.src[6]  = Whi; ca.dst[6]  = Whb;          ca.n[6]  = (int)HH;
    ca.src[7]  = Whg; ca.dst[7]  = Whb + HH;     ca.n[7]  = (int)HH;
    ca.src[8]  = Whf; ca.dst[8]  = Whb + 2 * HH; ca.n[8]  = (int)HH;
    ca.src[9]  = Who; ca.dst[9]  = Whb + 3 * HH; ca.n[9]  = (int)HH;
    ca.src[10] = Why; ca.dst[10] = Whyb;         ca.n[10] = (int)EH;

    hipLaunchKernelGGL(cast_kernel, dim3(1024, 11), dim3(256), 0, stream, ca);
    hipLaunchKernelGGL(gates_kernel, dim3(512), dim3(256), 0, stream,
                       Xb, Hb, Wxb, Whb, Bi, Bg, Bf, Bo, Z);

    float* y_out = (float*)d_out;
    float* c_out = y_out + BE;
    float* h_out = c_out + BH;
    hipLaunchKernelGGL(cell_kernel, dim3((unsigned)(BH / 1024)), dim3(256), 0, stream,
                       Z, c, c_out, h_out, HnB);

    float* ypart = (float*)Z;   // Z dead after cell_kernel
    hipLaunchKernelGGL(y_split_kernel, dim3(256), dim3(256), 0, stream,
                       HnB, Whyb, ypart);
    hipLaunchKernelGGL(y_reduce_kernel, dim3((unsigned)(BE / 1024)), dim3(256), 0, stream,
                       ypart, By, y_out);
}

// Round 5
// 267.003 us; speedup vs baseline: 1.0813x; 1.0753x over previous
//
#include <hip/hip_runtime.h>

#define B_SZ 1024
#define H_SZ 2048
#define E_SZ 1024

typedef float  f32x4 __attribute__((ext_vector_type(4)));
typedef short  s16x8 __attribute__((ext_vector_type(8)));

__device__ __forceinline__ unsigned short f2bf(float f) {
    unsigned u = __float_as_uint(f);
    u = u + 0x7fffu + ((u >> 16) & 1u);   // RNE
    return (unsigned short)(u >> 16);
}
__device__ __forceinline__ float bf2f(unsigned short s) {
    return __uint_as_float(((unsigned)s) << 16);
}
__device__ __forceinline__ float sigm(float v) {
    return 1.0f / (1.0f + __expf(-v));
}

__device__ __forceinline__ void gll(const unsigned short* g, unsigned short* l) {
    __builtin_amdgcn_global_load_lds(
        (const __attribute__((address_space(1))) unsigned int*)g,
        (__attribute__((address_space(3))) unsigned int*)l, 16, 0, 0);
}

// ---------------------------------------------------------------- cast pass
struct CastArgs {
    const float*    src[11];
    unsigned short* dst[11];
    int             n[11];
};

__global__ __launch_bounds__(256) void cast_kernel(CastArgs a) {
    const int arr = blockIdx.y;
    const int n = a.n[arr];
    const float* __restrict__ s = a.src[arr];
    unsigned short* __restrict__ d = a.dst[arr];
    const int stride = gridDim.x * 256 * 4;
    for (int i = (blockIdx.x * 256 + threadIdx.x) * 4; i < n; i += stride) {
        float4 v = *(const float4*)(s + i);
        ushort4 o;
        o.x = f2bf(v.x); o.y = f2bf(v.y); o.z = f2bf(v.z); o.w = f2bf(v.w);
        *(ushort4*)(d + i) = o;
    }
}

// ----------------------------------------- bf16 GEMM core, BK=64 + swizzle
// acc += A[128 rows @ m0][kLen] @ W[128 rows @ n0][kLen]^T, row stride = ld.
// LDS tile 128x64 (16 KB each). XOR swizzle: LDS slot (row, cb) holds global
// col-block cb ^ (row&7)  (cb = 8-element block). global_load_lds dest stays
// lane-contiguous (t*16B); only the SOURCE address is permuted. Fragment
// ds_read_b128 then hits all 32 banks 2-way (free) instead of 8-way.
__device__ __forceinline__ void gemm_accum64(
    const unsigned short* __restrict__ A,
    const unsigned short* __restrict__ W,
    int ld, int kLen, int m0, int n0,
    unsigned short* lA, unsigned short* lB,
    f32x4 acc[4][4], int t)
{
    const int lane = t & 63;
    const int w    = t >> 6;
    const int wr   = (w >> 1) << 6;   // wave row offset in 128-tile
    const int wc   = (w & 1) << 6;    // wave col offset
    const int lr   = lane & 15;
    const int q4   = lane >> 4;       // 0..3

    // staging: chunk c = t + 256p  ->  row = c>>3 (=srow+32p), colblk = t&7
    const int srow = t >> 3;                              // 0..31
    const int scol = ((t & 7) ^ (srow & 7)) << 3;         // swizzled col
    const unsigned short* gA = A + (size_t)(m0 + srow) * ld + scol;
    const unsigned short* gB = W + (size_t)(n0 + srow) * ld + scol;
    const size_t st32 = (size_t)32 * ld;

    // fragment read offsets (elements) for k-sub-step 0/1
    const int cb0 = ((q4    ) ^ (lr & 7)) << 3;
    const int cb1 = ((4 + q4) ^ (lr & 7)) << 3;

    for (int k0 = 0; k0 < kLen; k0 += 64) {
#pragma unroll
        for (int p = 0; p < 4; ++p)
            gll(gA + k0 + p * st32, lA + (t + 256 * p) * 8);
#pragma unroll
        for (int p = 0; p < 4; ++p)
            gll(gB + k0 + p * st32, lB + (t + 256 * p) * 8);
        __syncthreads();

#pragma unroll
        for (int ks = 0; ks < 2; ++ks) {
            const int cb = ks ? cb1 : cb0;
            s16x8 af[4], bfr[4];
#pragma unroll
            for (int i = 0; i < 4; ++i)
                af[i] = *(const s16x8*)(lA + (wr + i * 16 + lr) * 64 + cb);
#pragma unroll
            for (int j = 0; j < 4; ++j)
                bfr[j] = *(const s16x8*)(lB + (wc + j * 16 + lr) * 64 + cb);
#pragma unroll
            for (int i = 0; i < 4; ++i)
#pragma unroll
                for (int j = 0; j < 4; ++j)
                    acc[i][j] = __builtin_amdgcn_mfma_f32_16x16x32_bf16(
                        af[i], bfr[j], acc[i][j], 0, 0, 0);
        }
        __syncthreads();
    }
}

// -------------------------------------------------------------- gate GEMMs
// 512 blocks, XCD-swizzled (R2 layout: each XCD owns 8 contiguous nt).
__global__ __launch_bounds__(256) void gates_kernel(
    const unsigned short* __restrict__ Xb,
    const unsigned short* __restrict__ Hb,
    const unsigned short* __restrict__ Wxb,
    const unsigned short* __restrict__ Whb,
    const float* __restrict__ bi, const float* __restrict__ bg,
    const float* __restrict__ bff, const float* __restrict__ bo,
    unsigned short* __restrict__ Z)
{
    __shared__ unsigned short lA[128 * 64];
    __shared__ unsigned short lB[128 * 64];
    const int t   = threadIdx.x;
    const int b   = blockIdx.x;
    const int xcd = b & 7;
    const int i_  = b >> 3;                 // 0..63 within XCD
    const int nt  = xcd * 8 + (i_ >> 3);    // 0..63 weight tile (q,n0)
    const int m0  = (i_ & 7) * 128;
    const int q   = nt >> 4;
    const int n0  = (nt & 15) * 128;

    f32x4 acc[4][4] = {};
    gemm_accum64(Xb, Wxb + (size_t)q * H_SZ * E_SZ, E_SZ, E_SZ, m0, n0, lA, lB, acc, t);
    gemm_accum64(Hb, Whb + (size_t)q * H_SZ * H_SZ, H_SZ, H_SZ, m0, n0, lA, lB, acc, t);

    const float* bias = (q == 0) ? bi : (q == 1) ? bg : (q == 2) ? bff : bo;
    const int lane = t & 63, w = t >> 6;
    const int wr = (w >> 1) << 6, wc = (w & 1) << 6;
    const int lr = lane & 15, rq = (lane >> 4) << 2;
    unsigned short* Zq = Z + (size_t)q * B_SZ * H_SZ;
#pragma unroll
    for (int i = 0; i < 4; ++i) {
#pragma unroll
        for (int j = 0; j < 4; ++j) {
            const int n = n0 + wc + j * 16 + lr;
            const float bv = bias[n];
#pragma unroll
            for (int r = 0; r < 4; ++r) {
                const int m = m0 + wr + i * 16 + rq + r;
                const float v = acc[i][j][r] + bv;
                const float a = (q == 1) ? tanhf(v) : sigm(v);
                Zq[(size_t)m * H_SZ + n] = f2bf(a);
            }
        }
    }
}

// ------------------------------------------------------------ cell update
__global__ __launch_bounds__(256) void cell_kernel(
    const unsigned short* __restrict__ Z, const float* __restrict__ c,
    float* __restrict__ c_out, float* __restrict__ h_out,
    unsigned short* __restrict__ HnB)
{
    const size_t BH = (size_t)B_SZ * H_SZ;
    const int idx = (blockIdx.x * 256 + threadIdx.x) * 4;
    ushort4 iu = *(const ushort4*)(Z + idx);
    ushort4 gu = *(const ushort4*)(Z + BH + idx);
    ushort4 fu = *(const ushort4*)(Z + 2 * BH + idx);
    ushort4 ou = *(const ushort4*)(Z + 3 * BH + idx);
    float4 cv = *(const float4*)(c + idx);

    float cn[4], hn[4];
    cn[0] = bf2f(fu.x) * cv.x + bf2f(iu.x) * bf2f(gu.x);
    cn[1] = bf2f(fu.y) * cv.y + bf2f(iu.y) * bf2f(gu.y);
    cn[2] = bf2f(fu.z) * cv.z + bf2f(iu.z) * bf2f(gu.z);
    cn[3] = bf2f(fu.w) * cv.w + bf2f(iu.w) * bf2f(gu.w);
    hn[0] = bf2f(ou.x) * cn[0];
    hn[1] = bf2f(ou.y) * cn[1];
    hn[2] = bf2f(ou.z) * cn[2];
    hn[3] = bf2f(ou.w) * cn[3];

    *(float4*)(c_out + idx) = make_float4(cn[0], cn[1], cn[2], cn[3]);
    *(float4*)(h_out + idx) = make_float4(hn[0], hn[1], hn[2], hn[3]);
    ushort4 hb;
    hb.x = f2bf(hn[0]); hb.y = f2bf(hn[1]); hb.z = f2bf(hn[2]); hb.w = f2bf(hn[3]);
    *(ushort4*)(HnB + idx) = hb;
}

// ---------------------------------------------------- y GEMM, split-K by 4
// 256 blocks: (m 0..7) x (n 0..7) x (s 0..3), K-chunk = 512 (8 big steps).
__global__ __launch_bounds__(256) void y_split_kernel(
    const unsigned short* __restrict__ Hn,
    const unsigned short* __restrict__ Wy,
    float* __restrict__ part)
{
    __shared__ unsigned short lA[128 * 64];
    __shared__ unsigned short lB[128 * 64];
    const int t   = threadIdx.x;
    const int b   = blockIdx.x;
    const int xcd = b & 7;
    const int i_  = b >> 3;                 // 0..31 within XCD
    const int ns  = xcd * 4 + (i_ >> 3);    // 0..31: (n-tile, split)
    const int m0  = (i_ & 7) * 128;
    const int n0  = (ns >> 2) * 128;
    const int s   = ns & 3;

    f32x4 acc[4][4] = {};
    gemm_accum64(Hn + s * 512, Wy + s * 512, H_SZ, 512, m0, n0, lA, lB, acc, t);

    const int lane = t & 63, w = t >> 6;
    const int wr = (w >> 1) << 6, wc = (w & 1) << 6;
    const int lr = lane & 15, rq = (lane >> 4) << 2;
    float* P = part + (size_t)s * B_SZ * E_SZ;
#pragma unroll
    for (int i = 0; i < 4; ++i) {
#pragma unroll
        for (int j = 0; j < 4; ++j) {
            const int n = n0 + wc + j * 16 + lr;
#pragma unroll
            for (int r = 0; r < 4; ++r) {
                const int m = m0 + wr + i * 16 + rq + r;
                P[(size_t)m * E_SZ + n] = acc[i][j][r];
            }
        }
    }
}

__global__ __launch_bounds__(256) void y_reduce_kernel(
    const float* __restrict__ part, const float* __restrict__ by,
    float* __restrict__ yout)
{
    const size_t BE = (size_t)B_SZ * E_SZ;
    const int idx = (blockIdx.x * 256 + threadIdx.x) * 4;
    float4 a = *(const float4*)(part + idx);
    float4 b2 = *(const float4*)(part + BE + idx);
    float4 c2 = *(const float4*)(part + 2 * BE + idx);
    float4 d2 = *(const float4*)(part + 3 * BE + idx);
    const int col = idx & (E_SZ - 1);
    float4 bv = *(const float4*)(by + col);
    float4 o;
    o.x = tanhf(a.x + b2.x + c2.x + d2.x + bv.x);
    o.y = tanhf(a.y + b2.y + c2.y + d2.y + bv.y);
    o.z = tanhf(a.z + b2.z + c2.z + d2.z + bv.z);
    o.w = tanhf(a.w + b2.w + c2.w + d2.w + bv.w);
    *(float4*)(yout + idx) = o;
}

// ---------------------------------------------------------------- launch
extern "C" void kernel_launch(void* const* d_in, const int* in_sizes, int n_in,
                              void* d_out, int out_size, void* d_ws, size_t ws_size,
                              hipStream_t stream) {
    const float* x   = (const float*)d_in[0];
    const float* c   = (const float*)d_in[1];
    const float* h   = (const float*)d_in[2];
    const float* Wxi = (const float*)d_in[3];
    const float* Whi = (const float*)d_in[4];
    const float* Bi  = (const float*)d_in[5];
    const float* Wxg = (const float*)d_in[6];
    const float* Whg = (const float*)d_in[7];
    const float* Bg  = (const float*)d_in[8];
    const float* Wxf = (const float*)d_in[9];
    const float* Whf = (const float*)d_in[10];
    const float* Bf  = (const float*)d_in[11];
    const float* Wxo = (const float*)d_in[12];
    const float* Who = (const float*)d_in[13];
    const float* Bo  = (const float*)d_in[14];
    const float* Why = (const float*)d_in[15];
    const float* By  = (const float*)d_in[16];

    const size_t BE = (size_t)B_SZ * E_SZ, BH = (size_t)B_SZ * H_SZ;
    const size_t HE = (size_t)H_SZ * E_SZ, HH = (size_t)H_SZ * H_SZ;
    const size_t EH = (size_t)E_SZ * H_SZ;

    unsigned short* ws   = (unsigned short*)d_ws;
    unsigned short* Xb   = ws;                 // BE
    unsigned short* Hb   = Xb + BE;            // BH
    unsigned short* Wxb  = Hb + BH;            // 4*HE
    unsigned short* Whb  = Wxb + 4 * HE;       // 4*HH
    unsigned short* Whyb = Whb + 4 * HH;       // EH
    unsigned short* Z    = Whyb + EH;          // 4*BH bf16; later fp32 y-partials
    unsigned short* HnB  = Z + 4 * BH;         // BH

    CastArgs ca;
    ca.src[0]  = x;   ca.dst[0]  = Xb;           ca.n[0]  = (int)BE;
    ca.src[1]  = h;   ca.dst[1]  = Hb;           ca.n[1]  = (int)BH;
    ca.src[2]  = Wxi; ca.dst[2]  = Wxb;          ca.n[2]  = (int)HE;
    ca.src[3]  = Wxg; ca.dst[3]  = Wxb + HE;     ca.n[3]  = (int)HE;
    ca.src[4]  = Wxf; ca.dst[4]  = Wxb + 2 * HE; ca.n[4]  = (int)HE;
    ca.src[5]  = Wxo; ca.dst[5]  = Wxb + 3 * HE; ca.n[5]  = (int)HE;
    ca.src[6]  = Whi; ca.dst[6]  = Whb;          ca.n[6]  = (int)HH;
    ca.src[7]  = Whg; ca.dst[7]  = Whb + HH;     ca.n[7]  = (int)HH;
    ca.src[8]  = Whf; ca.dst[8]  = Whb + 2 * HH; ca.n[8]  = (int)HH;
    ca.src[9]  = Who; ca.dst[9]  = Whb + 3 * HH; ca.n[9]  = (int)HH;
    ca.src[10] = Why; ca.dst[10] = Whyb;         ca.n[10] = (int)EH;

    hipLaunchKernelGGL(cast_kernel, dim3(1024, 11), dim3(256), 0, stream, ca);
    hipLaunchKernelGGL(gates_kernel, dim3(512), dim3(256), 0, stream,
                       Xb, Hb, Wxb, Whb, Bi, Bg, Bf, Bo, Z);

    float* y_out = (float*)d_out;
    float* c_out = y_out + BE;
    float* h_out = c_out + BH;
    hipLaunchKernelGGL(cell_kernel, dim3((unsigned)(BH / 1024)), dim3(256), 0, stream,
                       Z, c, c_out, h_out, HnB);

    float* ypart = (float*)Z;   // Z dead after cell_kernel
    hipLaunchKernelGGL(y_split_kernel, dim3(256), dim3(256), 0, stream,
                       HnB, Whyb, ypart);
    hipLaunchKernelGGL(y_reduce_kernel, dim3((unsigned)(BE / 1024)), dim3(256), 0, stream,
                       ypart, By, y_out);
}